// Round 3
// baseline (326.124 us; speedup 1.0000x reference)
//
#include <hip/hip_runtime.h>

#define LROW 4096
#define NT   256
#define EPT  8             // elements per thread
#define TILE (NT * EPT)    // 2048
#define NC   (EPT + 2)     // cells incl 2 halo
#define NI   (EPT + 1)     // interfaces
#define GM1  0.4f

__device__ __forceinline__ float frcp(float x){ return __builtin_amdgcn_rcpf(x); }
__device__ __forceinline__ float frsq(float x){ return __builtin_amdgcn_rsqf(x); }

// Per-interface Roe flux, computed ONCE per interface and split into the
// lambda^- part (accumulated into the left cell's output) and lambda^+ part
// (right cell). This halves the Roe-average/projection work vs the previous
// per-cell-per-side formulation (8 one-sided evals -> 9 interfaces / 8 cells).
__global__ __launch_bounds__(NT)
void roe_kernel(const float* __restrict__ u, float* __restrict__ out)
{
    const int t    = threadIdx.x;
    const int base = blockIdx.x * TILE;
    const size_t rowoff = (size_t)blockIdx.y * (3 * LROW);
    const float* pr = u + rowoff;
    const float* pm = pr + LROW;
    const float* pE = pr + 2 * LROW;

    const int j0 = base + EPT * t;
    const int jm = (j0 == 0) ? 0 : j0 - 1;
    const int jp = (j0 + EPT >= LROW) ? (LROW - 1) : j0 + EPT;

    // 8 owned points via 2x float4 per component + 2 clamped halo scalars
    float4 rA = *(const float4*)(pr + j0);
    float4 rB = *(const float4*)(pr + j0 + 4);
    float4 mA = *(const float4*)(pm + j0);
    float4 mB = *(const float4*)(pm + j0 + 4);
    float4 EA = *(const float4*)(pE + j0);
    float4 EB = *(const float4*)(pE + j0 + 4);

    float rv[NC] = {pr[jm], rA.x, rA.y, rA.z, rA.w, rB.x, rB.y, rB.z, rB.w, pr[jp]};
    float mv[NC] = {pm[jm], mA.x, mA.y, mA.z, mA.w, mB.x, mB.y, mB.z, mB.w, pm[jp]};
    float Ev[NC] = {pE[jm], EA.x, EA.y, EA.z, EA.w, EB.x, EB.y, EB.z, EB.w, pE[jp]};

    // per-cell primitives: sqrt(rho), m/sqrt(rho), sqrt(rho)*H
    float sv[NC], qv[NC], sHv[NC];
#pragma unroll
    for (int k = 0; k < NC; k++) {
        float rs   = frsq(rv[k]);
        float rinv = rs * rs;
        float p    = GM1 * (Ev[k] - 0.5f * mv[k] * mv[k] * rinv);
        float H    = (Ev[k] + p) * rinv;
        sv[k]  = rv[k] * rs;
        qv[k]  = mv[k] * rs;
        sHv[k] = sv[k] * H;
    }

    float o0[EPT], o1[EPT], o2[EPT];
#pragma unroll
    for (int k = 0; k < EPT; k++) { o0[k] = 0.f; o1[k] = 0.f; o2[k] = 0.f; }

#pragma unroll
    for (int k = 0; k < NI; k++) {          // interface between cells k, k+1
        const float d0 = rv[k+1] - rv[k];
        const float d1 = mv[k+1] - mv[k];
        const float d2 = Ev[k+1] - Ev[k];

        // shared Roe average (computed once instead of twice)
        const float rS  = frcp(sv[k] + sv[k+1]);
        const float ua  = (qv[k]  + qv[k+1])  * rS;
        const float Ha  = (sHv[k] + sHv[k+1]) * rS;
        const float c2  = 0.5f * ua * ua;
        const float ca2 = GM1 * (Ha - c2);
        const float rca = frsq(ca2);
        const float ca  = ca2 * rca;
        const float k1  = GM1 * (rca * rca);      // 2*c1 = (g-1)/ca^2
        const float c3  = ca * (1.0f / GM1);
        const float tt  = ua * c3;
        const float p0  = c2 + tt, q0 = c2 - tt;
        const float p1  = ua + c3, q1 = ua - c3;
        const float h2  = fmaf(-ua, ua, Ha);      // ca*c3 - c2 = Ha - ua^2

        // characteristic projections, shared by both signs
        const float a0 = k1 * (fmaf(p0, d0, d2) - p1 * d1);
        const float a1 = (k1 + k1) * fmaf(h2, d0, fmaf(ua, d1, -d2));
        const float a2 = k1 * (fmaf(q0, d0, d2) - q1 * d1);

        const float l1 = ua - ca, l3 = ua + ca;
        const float uc = ua * ca;
        const float Hm = Ha - uc, Hp = Ha + uc;
        const float w1n = fminf(l1, 0.f);
        const float w2n = fminf(ua, 0.f);
        const float w3n = fminf(l3, 0.f);

        if (k >= 1) {          // lambda^- flux -> left cell k (output k-1)
            const float L0 = w1n * a0, L1 = w2n * a1, L2 = w3n * a2;
            o0[k-1] += L0 + L1 + L2;
            o1[k-1] += l1 * L0 + ua * L1 + l3 * L2;
            o2[k-1] += Hm * L0 + c2 * L1 + Hp * L2;
        }
        if (k <= EPT - 1) {    // lambda^+ flux -> right cell k+1 (output k)
            const float w1p = l1 - w1n, w2p = ua - w2n, w3p = l3 - w3n;
            const float L0 = w1p * a0, L1 = w2p * a1, L2 = w3p * a2;
            o0[k] += L0 + L1 + L2;
            o1[k] += l1 * L0 + ua * L1 + l3 * L2;
            o2[k] += Hm * L0 + c2 * L1 + Hp * L2;
        }
    }

    const float SC = -100.0f;  // -1/(2*DX)
    float* qo = out + rowoff;
    *(float4*)(qo + j0)     = make_float4(SC*o0[0], SC*o0[1], SC*o0[2], SC*o0[3]);
    *(float4*)(qo + j0 + 4) = make_float4(SC*o0[4], SC*o0[5], SC*o0[6], SC*o0[7]);
    *(float4*)(qo + LROW + j0)     = make_float4(SC*o1[0], SC*o1[1], SC*o1[2], SC*o1[3]);
    *(float4*)(qo + LROW + j0 + 4) = make_float4(SC*o1[4], SC*o1[5], SC*o1[6], SC*o1[7]);
    *(float4*)(qo + 2*LROW + j0)     = make_float4(SC*o2[0], SC*o2[1], SC*o2[2], SC*o2[3]);
    *(float4*)(qo + 2*LROW + j0 + 4) = make_float4(SC*o2[4], SC*o2[5], SC*o2[6], SC*o2[7]);
}

extern "C" void kernel_launch(void* const* d_in, const int* in_sizes, int n_in,
                              void* d_out, int out_size, void* d_ws, size_t ws_size,
                              hipStream_t stream)
{
    const float* u = (const float*)d_in[0];
    float* out = (float*)d_out;
    const int M = in_sizes[0] / (3 * LROW); // 4096 rows
    dim3 grid(LROW / TILE, M);
    roe_kernel<<<grid, NT, 0, stream>>>(u, out);
}